// Round 1
// baseline (3807.733 us; speedup 1.0000x reference)
//
#include <hip/hip_runtime.h>
#include <math.h>

#define HIDDEN 2048
#define NH 16
#define HD 128
#define NB 2
#define SEQ 2048

// ==================== RoPE tables (double-precision trig) ====================
// 2048 positions x 64 freqs. Double pow/cos/sin: only 131k threads, negligible,
// and avoids fp32 range-reduction error at angles up to 2047 rad.
__global__ void k_rope_tables(float* __restrict__ ct, float* __restrict__ st) {
    int idx = blockIdx.x * 256 + threadIdx.x;   // exactly SEQ*64 threads
    int s = idx >> 6, d = idx & 63;
    double inv = pow(10000.0, -(double)d * (1.0 / 64.0));
    double ang = (double)s * inv;
    ct[idx] = (float)cos(ang);
    st[idx] = (float)sin(ang);
}

// ==================== fp32 GEMM:  C[m][n] = sum_k A[m][k]*W[n][k] + bias[n] ==
// Both operands k-contiguous (einsum 'bsh,oh->bso' == A @ W^T).
// 128x128 tile, BK=16, 256 threads (16x16), 8x8 per thread.
// LDS transposed [k][m] with pad 132 (16B-aligned rows, 2-way bank alias only).
// headLayout=1: scatter into (B,NH,S,HD) for attention; else row-major (M,N).
__global__ __launch_bounds__(256)
void k_gemm_nt(const float* __restrict__ A, const float* __restrict__ W,
               const float* __restrict__ bias, float* __restrict__ out,
               const int headLayout) {
    __shared__ float As[16][132];
    __shared__ float Bs[16][132];
    const int tid = threadIdx.x;
    const int tx = tid & 15, ty = tid >> 4;
    const int m0 = blockIdx.x << 7;
    const int n0 = blockIdx.y << 7;
    const int lr = tid >> 2;            // 0..63
    const int lc = (tid & 3) << 2;      // 0,4,8,12
    const float* Ap = A + (size_t)(m0 + lr) * HIDDEN + lc;
    const float* Wp = W + (size_t)(n0 + lr) * HIDDEN + lc;

    float acc[8][8];
#pragma unroll
    for (int i = 0; i < 8; i++)
#pragma unroll
        for (int j = 0; j < 8; j++) acc[i][j] = 0.f;

    for (int kt = 0; kt < HIDDEN; kt += 16) {
        // issue global loads before the sync so they overlap previous compute
        float4 a0 = *(const float4*)(Ap + kt);
        float4 a1 = *(const float4*)(Ap + kt + (size_t)64 * HIDDEN);
        float4 w0 = *(const float4*)(Wp + kt);
        float4 w1 = *(const float4*)(Wp + kt + (size_t)64 * HIDDEN);
        __syncthreads();   // previous iteration's LDS reads done
        As[lc + 0][lr] = a0.x; As[lc + 1][lr] = a0.y; As[lc + 2][lr] = a0.z; As[lc + 3][lr] = a0.w;
        As[lc + 0][lr + 64] = a1.x; As[lc + 1][lr + 64] = a1.y; As[lc + 2][lr + 64] = a1.z; As[lc + 3][lr + 64] = a1.w;
        Bs[lc + 0][lr] = w0.x; Bs[lc + 1][lr] = w0.y; Bs[lc + 2][lr] = w0.z; Bs[lc + 3][lr] = w0.w;
        Bs[lc + 0][lr + 64] = w1.x; Bs[lc + 1][lr + 64] = w1.y; Bs[lc + 2][lr + 64] = w1.z; Bs[lc + 3][lr + 64] = w1.w;
        __syncthreads();
#pragma unroll
        for (int kk = 0; kk < 16; kk++) {
            float a[8], b[8];
            *(float4*)(a)     = *(const float4*)&As[kk][ty << 3];
            *(float4*)(a + 4) = *(const float4*)&As[kk][(ty << 3) + 4];
            *(float4*)(b)     = *(const float4*)&Bs[kk][tx << 3];
            *(float4*)(b + 4) = *(const float4*)&Bs[kk][(tx << 3) + 4];
#pragma unroll
            for (int i = 0; i < 8; i++)
#pragma unroll
                for (int j = 0; j < 8; j++)
                    acc[i][j] = fmaf(a[i], b[j], acc[i][j]);
        }
    }

    float4 b0 = *(const float4*)(bias + n0 + (tx << 3));
    float4 b1 = *(const float4*)(bias + n0 + (tx << 3) + 4);
    if (headLayout) {
        // tile n-range is exactly one head (128 cols); rows stay within one batch
        const int h = n0 >> 7;
        const int bb = m0 >> 11;
        const int sbase = m0 & (SEQ - 1);
#pragma unroll
        for (int i = 0; i < 8; i++) {
            int s = sbase + (ty << 3) + i;
            float* dst = out + (((size_t)bb * NH + h) * SEQ + s) * HD + (tx << 3);
            float4 v0 = make_float4(acc[i][0] + b0.x, acc[i][1] + b0.y, acc[i][2] + b0.z, acc[i][3] + b0.w);
            float4 v1 = make_float4(acc[i][4] + b1.x, acc[i][5] + b1.y, acc[i][6] + b1.z, acc[i][7] + b1.w);
            *(float4*)dst = v0;
            *(float4*)(dst + 4) = v1;
        }
    } else {
#pragma unroll
        for (int i = 0; i < 8; i++) {
            int m = m0 + (ty << 3) + i;
            float* dst = out + (size_t)m * HIDDEN + n0 + (tx << 3);
            float4 v0 = make_float4(acc[i][0] + b0.x, acc[i][1] + b0.y, acc[i][2] + b0.z, acc[i][3] + b0.w);
            float4 v1 = make_float4(acc[i][4] + b1.x, acc[i][5] + b1.y, acc[i][6] + b1.z, acc[i][7] + b1.w);
            *(float4*)dst = v0;
            *(float4*)(dst + 4) = v1;
        }
    }
}

// ==================== RoPE apply (in-place on q_ws, k_ws) ====================
// one thread per (b,h,s,d<64) pair; handles d and d+64 together.
__global__ void k_rope_apply(float* __restrict__ q, float* __restrict__ k,
                             const float* __restrict__ ct, const float* __restrict__ st) {
    int idx = blockIdx.x * 256 + threadIdx.x;   // exactly NB*NH*SEQ*64 threads
    int d = idx & 63;
    int s = (idx >> 6) & (SEQ - 1);
    int bh = idx >> 17;
    size_t base = ((size_t)bh * SEQ + s) * HD;
    float c = ct[(s << 6) + d], sn = st[(s << 6) + d];
    float q0 = q[base + d], q1 = q[base + d + 64];
    q[base + d]      = q0 * c - q1 * sn;
    q[base + d + 64] = q1 * c + q0 * sn;
    float k0 = k[base + d], k1 = k[base + d + 64];
    k[base + d]      = k0 * c - k1 * sn;
    k[base + d + 64] = k1 * c + k0 * sn;
}

// ==================== Flash attention (fp32, online softmax) =================
// Block = 256 threads = (16 tx, 16 ty), handles 64 q rows of one (b,h).
// K chunks of 64 rows share one LDS buffer with V (V prefetched into registers
// behind the score compute). Scores 4x4/thread: rows 16i+ty, cols 16j+tx
// (keeps K LDS reads at 2-way bank aliasing == free). P goes through LDS for PV.
__global__ __launch_bounds__(256)
void k_flash(const float* __restrict__ Q, const float* __restrict__ K,
             const float* __restrict__ V, float* __restrict__ ctx) {
    __shared__ float Qs[64][132];
    __shared__ float KV[64][132];
    __shared__ float Ps[64][68];
    const int tid = threadIdx.x;
    const int tx = tid & 15, ty = tid >> 4;
    const int qt = blockIdx.x, h = blockIdx.y, b = blockIdx.z;
    const size_t hb = ((size_t)(b * NH + h)) * SEQ * HD;
    const float* Qh = Q + hb + ((size_t)qt << 6) * HD;
    const float* Kh = K + hb;
    const float* Vh = V + hb;
    const int lrr = tid >> 5;          // 0..7
    const int lcc = (tid & 31) << 2;   // 0..124

    // load Q tile, pre-scaled by 1/sqrt(HD)
#pragma unroll
    for (int l = 0; l < 8; l++) {
        int r = (l << 3) + lrr;
        float4 v = *(const float4*)(Qh + r * HD + lcc);
        const float sc_ = 0.08838834764831845f;
        v.x *= sc_; v.y *= sc_; v.z *= sc_; v.w *= sc_;
        *(float4*)&Qs[r][lcc] = v;
    }

    float m_run[4], l_run[4], acc[4][8];
#pragma unroll
    for (int i = 0; i < 4; i++) {
        m_run[i] = -1e30f; l_run[i] = 0.f;
#pragma unroll
        for (int j = 0; j < 8; j++) acc[i][j] = 0.f;
    }

    for (int kt = 0; kt < SEQ; kt += 64) {
        // prefetch V chunk into registers (hidden behind score compute)
        float4 vreg[8];
#pragma unroll
        for (int l = 0; l < 8; l++)
            vreg[l] = *(const float4*)(Vh + (size_t)(kt + (l << 3) + lrr) * HD + lcc);
        __syncthreads();   // previous chunk's PV reads of KV/Ps complete
#pragma unroll
        for (int l = 0; l < 8; l++)
            *(float4*)&KV[(l << 3) + lrr][lcc] =
                *(const float4*)(Kh + (size_t)(kt + (l << 3) + lrr) * HD + lcc);
        __syncthreads();

        // ---- scores: sc4[i][j] = q_row(16i+ty) . k_row(16j+tx) ----
        float sc4[4][4];
#pragma unroll
        for (int i = 0; i < 4; i++)
#pragma unroll
            for (int j = 0; j < 4; j++) sc4[i][j] = 0.f;
#pragma unroll 4
        for (int kk = 0; kk < HD; kk += 4) {
            float qa[16], kb[16];
#pragma unroll
            for (int i = 0; i < 4; i++)
                *(float4*)(qa + 4 * i) = *(const float4*)&Qs[(i << 4) + ty][kk];
#pragma unroll
            for (int j = 0; j < 4; j++)
                *(float4*)(kb + 4 * j) = *(const float4*)&KV[(j << 4) + tx][kk];
#pragma unroll
            for (int i = 0; i < 4; i++)
#pragma unroll
                for (int j = 0; j < 4; j++) {
                    sc4[i][j] = fmaf(qa[4 * i + 0], kb[4 * j + 0], sc4[i][j]);
                    sc4[i][j] = fmaf(qa[4 * i + 1], kb[4 * j + 1], sc4[i][j]);
                    sc4[i][j] = fmaf(qa[4 * i + 2], kb[4 * j + 2], sc4[i][j]);
                    sc4[i][j] = fmaf(qa[4 * i + 3], kb[4 * j + 3], sc4[i][j]);
                }
        }

        // ---- online softmax (row stats shared across the 16-lane tx group) ----
#pragma unroll
        for (int i = 0; i < 4; i++) {
            float mc = fmaxf(fmaxf(sc4[i][0], sc4[i][1]), fmaxf(sc4[i][2], sc4[i][3]));
            mc = fmaxf(mc, __shfl_xor(mc, 1));
            mc = fmaxf(mc, __shfl_xor(mc, 2));
            mc = fmaxf(mc, __shfl_xor(mc, 4));
            mc = fmaxf(mc, __shfl_xor(mc, 8));
            float mn = fmaxf(m_run[i], mc);
            float al = __expf(m_run[i] - mn);
            m_run[i] = mn;
            float ls = 0.f;
#pragma unroll
            for (int j = 0; j < 4; j++) {
                float p = __expf(sc4[i][j] - mn);
                Ps[(i << 4) + ty][(j << 4) + tx] = p;
                ls += p;
            }
            ls += __shfl_xor(ls, 1);
            ls += __shfl_xor(ls, 2);
            ls += __shfl_xor(ls, 4);
            ls += __shfl_xor(ls, 8);
            l_run[i] = l_run[i] * al + ls;
#pragma unroll
            for (int j = 0; j < 8; j++) acc[i][j] *= al;
        }
        __syncthreads();   // K reads done + Ps visible
        // V registers -> LDS
#pragma unroll
        for (int l = 0; l < 8; l++)
            *(float4*)&KV[(l << 3) + lrr][lcc] = vreg[l];
        __syncthreads();

        // ---- PV: acc[i][jd] += sum_jr P[row][jr] * V[jr][tx*8+jd] ----
#pragma unroll 2
        for (int jr = 0; jr < 64; jr += 4) {
            float vv[4][8];
#pragma unroll
            for (int u = 0; u < 4; u++) {
                *(float4*)&vv[u][0] = *(const float4*)&KV[jr + u][tx << 3];
                *(float4*)&vv[u][4] = *(const float4*)&KV[jr + u][(tx << 3) + 4];
            }
#pragma unroll
            for (int i = 0; i < 4; i++) {
                float pr[4];
                *(float4*)pr = *(const float4*)&Ps[(i << 4) + ty][jr];
#pragma unroll
                for (int u = 0; u < 4; u++)
#pragma unroll
                    for (int jd = 0; jd < 8; jd++)
                        acc[i][jd] = fmaf(pr[u], vv[u][jd], acc[i][jd]);
            }
        }
    }

    // ---- normalize and write ctx in (B,S,H) layout for the O-projection ----
#pragma unroll
    for (int i = 0; i < 4; i++) {
        float inv = 1.0f / l_run[i];
        int s = (qt << 6) + (i << 4) + ty;
        float* dst = ctx + ((size_t)b * SEQ + s) * HIDDEN + (h << 7) + (tx << 3);
        float4 o0 = make_float4(acc[i][0] * inv, acc[i][1] * inv, acc[i][2] * inv, acc[i][3] * inv);
        float4 o1 = make_float4(acc[i][4] * inv, acc[i][5] * inv, acc[i][6] * inv, acc[i][7] * inv);
        *(float4*)dst = o0;
        *(float4*)(dst + 4) = o1;
    }
}

// ==================== launch =================================================
extern "C" void kernel_launch(void* const* d_in, const int* in_sizes, int n_in,
                              void* d_out, int out_size, void* d_ws, size_t ws_size,
                              hipStream_t stream) {
    const float* X  = (const float*)d_in[0];
    const float* Wq = (const float*)d_in[1];
    const float* bq = (const float*)d_in[2];
    const float* Wk = (const float*)d_in[3];
    const float* bk = (const float*)d_in[4];
    const float* Wv = (const float*)d_in[5];
    const float* bv = (const float*)d_in[6];
    const float* Wo = (const float*)d_in[7];
    const float* bo = (const float*)d_in[8];
    float* out = (float*)d_out;

    // workspace layout (floats): q | k | v | ctx | cos | sin  = ~135 MB
    const size_t QS = (size_t)NB * NH * SEQ * HD;   // 8,388,608
    float* q_ws = (float*)d_ws;
    float* k_ws = q_ws + QS;
    float* v_ws = k_ws + QS;
    float* c_ws = v_ws + QS;
    float* cost = c_ws + QS;
    float* sint = cost + (size_t)SEQ * 64;

    k_rope_tables<<<(SEQ * 64) / 256, 256, 0, stream>>>(cost, sint);

    dim3 g(32, 16);   // M=4096 / 128, N=2048 / 128
    k_gemm_nt<<<g, 256, 0, stream>>>(X, Wq, bq, q_ws, 1);
    k_gemm_nt<<<g, 256, 0, stream>>>(X, Wk, bk, k_ws, 1);
    k_gemm_nt<<<g, 256, 0, stream>>>(X, Wv, bv, v_ws, 1);

    k_rope_apply<<<(NB * NH * SEQ * 64) / 256, 256, 0, stream>>>(q_ws, k_ws, cost, sint);

    k_flash<<<dim3(SEQ / 64, NH, NB), 256, 0, stream>>>(q_ws, k_ws, v_ws, c_ws);

    k_gemm_nt<<<g, 256, 0, stream>>>(c_ws, Wo, bo, out, 0);
}

// Round 2
// 2054.683 us; speedup vs baseline: 1.8532x; 1.8532x over previous
//
#include <hip/hip_runtime.h>
#include <math.h>

#define HIDDEN 2048
#define NH 16
#define HD 128
#define NB 2
#define SEQ 2048
#define K_DIM 2048

typedef unsigned int u32;
typedef unsigned short ushort_t;
typedef __bf16 bf16x8 __attribute__((ext_vector_type(8)));
typedef float f32x4 __attribute__((ext_vector_type(4)));

// ---------- fp32 -> (bf16 hi, bf16 lo) split, RNE both halves ----------
__device__ __forceinline__ void split1(float x, unsigned short& h, unsigned short& l) {
    u32 u = __float_as_uint(x);
    u32 hr = (u + 0x7FFFu + ((u >> 16) & 1u)) >> 16;
    h = (unsigned short)hr;
    float r = x - __uint_as_float(hr << 16);
    u32 u2 = __float_as_uint(r);
    l = (unsigned short)((u2 + 0x7FFFu + ((u2 >> 16) & 1u)) >> 16);
}

__device__ __forceinline__ void gl_lds16(const void* g, void* l) {
    __builtin_amdgcn_global_load_lds(
        (const __attribute__((address_space(1))) u32*)g,
        (__attribute__((address_space(3))) u32*)l, 16, 0, 0);
}

// ==================== RoPE tables (double-precision trig) ====================
__global__ void k_rope_tables(float* __restrict__ ct, float* __restrict__ st) {
    int idx = blockIdx.x * 256 + threadIdx.x;   // exactly SEQ*64 threads
    int s = idx >> 6, d = idx & 63;
    double inv = pow(10000.0, -(double)d * (1.0 / 64.0));
    double ang = (double)s * inv;
    ct[idx] = (float)cos(ang);
    st[idx] = (float)sin(ang);
}

// ==================== fp32 -> bf16 hi/lo split kernel ========================
__global__ void k_split(const float4* __restrict__ src, ushort4* __restrict__ hi,
                        ushort4* __restrict__ lo) {
    int idx = blockIdx.x * 256 + threadIdx.x;
    float4 x = src[idx];
    ushort4 h, l;
    split1(x.x, h.x, l.x);
    split1(x.y, h.y, l.y);
    split1(x.z, h.z, l.z);
    split1(x.w, h.w, l.w);
    hi[idx] = h;
    lo[idx] = l;
}

// ==================== bf16x3 MFMA GEMM =======================================
// C[m][n] = sum_k A[m][k] * W[n][k] + bias[n]  (both K-contiguous, NT form)
// A given as hi/lo bf16 pair, W likewise. acc += Ah*Wh + Ah*Wl + Al*Wh.
// 128x128 tile, BK=32, 256 threads = 4 waves (2x2), 4x4 frags of 16x16x32/wave.
// Staging via global_load_lds width=16: LDS tile row-major [128][32] bf16,
// contiguous (layout forced by wave-uniform-base + lane*16 semantics).
// headLayout=1: scatter into (B,NH,S,HD); else row-major (M,N).
__global__ __launch_bounds__(256)
void k_gemm_mfma(const ushort_t* __restrict__ Ah, const ushort_t* __restrict__ Al,
                 const ushort_t* __restrict__ Bh, const ushort_t* __restrict__ Bl,
                 const float* __restrict__ bias, float* __restrict__ out,
                 const int headLayout) {
    __shared__ ushort_t lds[4][128 * 32];   // Ah | Al | Bh | Bl tiles, 32 KB
    const int tid = threadIdx.x;
    const int lane = tid & 63;
    const int w = tid >> 6;
    const int wm = w & 1, wn = w >> 1;
    const int quad = lane >> 4;
    const int l15 = lane & 15;
    const int m0 = blockIdx.x << 7;
    const int n0 = blockIdx.y << 7;

    // wave w stages matrix w: 8 instrs x 1KB = 128 rows x 32 elems (64B/row)
    const ushort_t* src = (w == 0) ? Ah : (w == 1) ? Al : (w == 2) ? Bh : Bl;
    const int rbase = (w < 2) ? m0 : n0;
    const int lrow = lane >> 2;          // 0..15 (row within 16-row group)
    const int lk = (lane & 3) << 3;      // 0,8,16,24 (elem offset, 16B chunks)
    const ushort_t* gp[8];
    ushort_t* lp[8];
#pragma unroll
    for (int i = 0; i < 8; i++) {
        gp[i] = src + (size_t)(rbase + i * 16 + lrow) * K_DIM + lk;
        lp[i] = &lds[w][i * 512];        // wave-uniform LDS base per instr
    }

    f32x4 acc[4][4];
#pragma unroll
    for (int i = 0; i < 4; i++)
#pragma unroll
        for (int j = 0; j < 4; j++) acc[i][j] = (f32x4){0.f, 0.f, 0.f, 0.f};

    const int aoff = (wm * 64 + l15) * 32 + quad * 8;
    const int boff = (wn * 64 + l15) * 32 + quad * 8;

    // prologue: stage kt=0, read first fragments
#pragma unroll
    for (int i = 0; i < 8; i++) gl_lds16(gp[i], lp[i]);
    __syncthreads();
    bf16x8 ah[4], al[4], bh[4], bl[4];
#pragma unroll
    for (int f = 0; f < 4; f++) {
        ah[f] = *(const bf16x8*)&lds[0][aoff + f * 512];
        al[f] = *(const bf16x8*)&lds[1][aoff + f * 512];
        bh[f] = *(const bf16x8*)&lds[2][boff + f * 512];
        bl[f] = *(const bf16x8*)&lds[3][boff + f * 512];
    }

    for (int kt = 32; kt <= K_DIM; kt += 32) {
        __syncthreads();                 // all waves' frag ds_reads done
        if (kt < K_DIM) {
#pragma unroll
            for (int i = 0; i < 8; i++) gl_lds16(gp[i] + kt, lp[i]);
        }
        // MFMAs overlap the in-flight global_load_lds
#pragma unroll
        for (int fm = 0; fm < 4; fm++)
#pragma unroll
            for (int fn = 0; fn < 4; fn++) {
                acc[fm][fn] = __builtin_amdgcn_mfma_f32_16x16x32_bf16(ah[fm], bh[fn], acc[fm][fn], 0, 0, 0);
                acc[fm][fn] = __builtin_amdgcn_mfma_f32_16x16x32_bf16(ah[fm], bl[fn], acc[fm][fn], 0, 0, 0);
                acc[fm][fn] = __builtin_amdgcn_mfma_f32_16x16x32_bf16(al[fm], bh[fn], acc[fm][fn], 0, 0, 0);
            }
        if (kt < K_DIM) {
            __syncthreads();             // staging complete (vmcnt drain)
#pragma unroll
            for (int f = 0; f < 4; f++) {
                ah[f] = *(const bf16x8*)&lds[0][aoff + f * 512];
                al[f] = *(const bf16x8*)&lds[1][aoff + f * 512];
                bh[f] = *(const bf16x8*)&lds[2][boff + f * 512];
                bl[f] = *(const bf16x8*)&lds[3][boff + f * 512];
            }
        }
    }

    // epilogue: C/D layout col=lane&15, row=quad*4+reg  [m89/m91-verified]
    float bcolv[4];
#pragma unroll
    for (int fn = 0; fn < 4; fn++) bcolv[fn] = bias[n0 + wn * 64 + fn * 16 + l15];

    if (headLayout) {
        const int h = n0 >> 7;                    // 128-wide n-tile == one head
        const int bb = m0 >> 11;
        const int sb = (m0 & (SEQ - 1)) + wm * 64 + quad * 4;
        const int d = wn * 64 + l15;
        float* obase = out + ((size_t)(bb * NH + h) * SEQ) * HD;
#pragma unroll
        for (int fm = 0; fm < 4; fm++)
#pragma unroll
            for (int fn = 0; fn < 4; fn++)
#pragma unroll
                for (int r = 0; r < 4; r++)
                    obase[(size_t)(sb + fm * 16 + r) * HD + d + fn * 16] =
                        acc[fm][fn][r] + bcolv[fn];
    } else {
        const int mb = m0 + wm * 64 + quad * 4;
        const int nb = n0 + wn * 64 + l15;
#pragma unroll
        for (int fm = 0; fm < 4; fm++)
#pragma unroll
            for (int fn = 0; fn < 4; fn++)
#pragma unroll
                for (int r = 0; r < 4; r++)
                    out[(size_t)(mb + fm * 16 + r) * HIDDEN + nb + fn * 16] =
                        acc[fm][fn][r] + bcolv[fn];
    }
}

// ==================== RoPE apply (in-place on q_ws, k_ws) ====================
__global__ void k_rope_apply(float* __restrict__ q, float* __restrict__ k,
                             const float* __restrict__ ct, const float* __restrict__ st) {
    int idx = blockIdx.x * 256 + threadIdx.x;   // exactly NB*NH*SEQ*64 threads
    int d = idx & 63;
    int s = (idx >> 6) & (SEQ - 1);
    int bh = idx >> 17;
    size_t base = ((size_t)bh * SEQ + s) * HD;
    float c = ct[(s << 6) + d], sn = st[(s << 6) + d];
    float q0 = q[base + d], q1 = q[base + d + 64];
    q[base + d]      = q0 * c - q1 * sn;
    q[base + d + 64] = q1 * c + q0 * sn;
    float k0 = k[base + d], k1 = k[base + d + 64];
    k[base + d]      = k0 * c - k1 * sn;
    k[base + d + 64] = k1 * c + k0 * sn;
}

// ==================== Flash attention (fp32, online softmax) =================
// Unchanged from R1 except the epilogue writes ctx directly as bf16 hi/lo
// (split-precision input for the MFMA O-projection).
__global__ __launch_bounds__(256)
void k_flash(const float* __restrict__ Q, const float* __restrict__ K,
             const float* __restrict__ V,
             ushort_t* __restrict__ ch, ushort_t* __restrict__ cl) {
    __shared__ float Qs[64][132];
    __shared__ float KV[64][132];
    __shared__ float Ps[64][68];
    const int tid = threadIdx.x;
    const int tx = tid & 15, ty = tid >> 4;
    const int qt = blockIdx.x, h = blockIdx.y, b = blockIdx.z;
    const size_t hb = ((size_t)(b * NH + h)) * SEQ * HD;
    const float* Qh = Q + hb + ((size_t)qt << 6) * HD;
    const float* Kh = K + hb;
    const float* Vh = V + hb;
    const int lrr = tid >> 5;          // 0..7
    const int lcc = (tid & 31) << 2;   // 0..124

#pragma unroll
    for (int l = 0; l < 8; l++) {
        int r = (l << 3) + lrr;
        float4 v = *(const float4*)(Qh + r * HD + lcc);
        const float sc_ = 0.08838834764831845f;
        v.x *= sc_; v.y *= sc_; v.z *= sc_; v.w *= sc_;
        *(float4*)&Qs[r][lcc] = v;
    }

    float m_run[4], l_run[4], acc[4][8];
#pragma unroll
    for (int i = 0; i < 4; i++) {
        m_run[i] = -1e30f; l_run[i] = 0.f;
#pragma unroll
        for (int j = 0; j < 8; j++) acc[i][j] = 0.f;
    }

    for (int kt = 0; kt < SEQ; kt += 64) {
        float4 vreg[8];
#pragma unroll
        for (int l = 0; l < 8; l++)
            vreg[l] = *(const float4*)(Vh + (size_t)(kt + (l << 3) + lrr) * HD + lcc);
        __syncthreads();
#pragma unroll
        for (int l = 0; l < 8; l++)
            *(float4*)&KV[(l << 3) + lrr][lcc] =
                *(const float4*)(Kh + (size_t)(kt + (l << 3) + lrr) * HD + lcc);
        __syncthreads();

        float sc4[4][4];
#pragma unroll
        for (int i = 0; i < 4; i++)
#pragma unroll
            for (int j = 0; j < 4; j++) sc4[i][j] = 0.f;
#pragma unroll 4
        for (int kk = 0; kk < HD; kk += 4) {
            float qa[16], kb[16];
#pragma unroll
            for (int i = 0; i < 4; i++)
                *(float4*)(qa + 4 * i) = *(const float4*)&Qs[(i << 4) + ty][kk];
#pragma unroll
            for (int j = 0; j < 4; j++)
                *(float4*)(kb + 4 * j) = *(const float4*)&KV[(j << 4) + tx][kk];
#pragma unroll
            for (int i = 0; i < 4; i++)
#pragma unroll
                for (int j = 0; j < 4; j++) {
                    sc4[i][j] = fmaf(qa[4 * i + 0], kb[4 * j + 0], sc4[i][j]);
                    sc4[i][j] = fmaf(qa[4 * i + 1], kb[4 * j + 1], sc4[i][j]);
                    sc4[i][j] = fmaf(qa[4 * i + 2], kb[4 * j + 2], sc4[i][j]);
                    sc4[i][j] = fmaf(qa[4 * i + 3], kb[4 * j + 3], sc4[i][j]);
                }
        }

#pragma unroll
        for (int i = 0; i < 4; i++) {
            float mc = fmaxf(fmaxf(sc4[i][0], sc4[i][1]), fmaxf(sc4[i][2], sc4[i][3]));
            mc = fmaxf(mc, __shfl_xor(mc, 1));
            mc = fmaxf(mc, __shfl_xor(mc, 2));
            mc = fmaxf(mc, __shfl_xor(mc, 4));
            mc = fmaxf(mc, __shfl_xor(mc, 8));
            float mn = fmaxf(m_run[i], mc);
            float al = __expf(m_run[i] - mn);
            m_run[i] = mn;
            float ls = 0.f;
#pragma unroll
            for (int j = 0; j < 4; j++) {
                float p = __expf(sc4[i][j] - mn);
                Ps[(i << 4) + ty][(j << 4) + tx] = p;
                ls += p;
            }
            ls += __shfl_xor(ls, 1);
            ls += __shfl_xor(ls, 2);
            ls += __shfl_xor(ls, 4);
            ls += __shfl_xor(ls, 8);
            l_run[i] = l_run[i] * al + ls;
#pragma unroll
            for (int j = 0; j < 8; j++) acc[i][j] *= al;
        }
        __syncthreads();
#pragma unroll
        for (int l = 0; l < 8; l++)
            *(float4*)&KV[(l << 3) + lrr][lcc] = vreg[l];
        __syncthreads();

#pragma unroll 2
        for (int jr = 0; jr < 64; jr += 4) {
            float vv[4][8];
#pragma unroll
            for (int u = 0; u < 4; u++) {
                *(float4*)&vv[u][0] = *(const float4*)&KV[jr + u][tx << 3];
                *(float4*)&vv[u][4] = *(const float4*)&KV[jr + u][(tx << 3) + 4];
            }
#pragma unroll
            for (int i = 0; i < 4; i++) {
                float pr[4];
                *(float4*)pr = *(const float4*)&Ps[(i << 4) + ty][jr];
#pragma unroll
                for (int u = 0; u < 4; u++)
#pragma unroll
                    for (int jd = 0; jd < 8; jd++)
                        acc[i][jd] = fmaf(pr[u], vv[u][jd], acc[i][jd]);
            }
        }
    }

    // normalize + split-write ctx (B,S,H) as bf16 hi/lo for the O-projection
#pragma unroll
    for (int i = 0; i < 4; i++) {
        float inv = 1.0f / l_run[i];
        int s = (qt << 6) + (i << 4) + ty;
        size_t base = ((size_t)b * SEQ + s) * HIDDEN + (h << 7) + (tx << 3);
        ushort4 h0, h1, l0, l1;
        split1(acc[i][0] * inv, h0.x, l0.x);
        split1(acc[i][1] * inv, h0.y, l0.y);
        split1(acc[i][2] * inv, h0.z, l0.z);
        split1(acc[i][3] * inv, h0.w, l0.w);
        split1(acc[i][4] * inv, h1.x, l1.x);
        split1(acc[i][5] * inv, h1.y, l1.y);
        split1(acc[i][6] * inv, h1.z, l1.z);
        split1(acc[i][7] * inv, h1.w, l1.w);
        *(ushort4*)&ch[base] = h0;
        *(ushort4*)&ch[base + 4] = h1;
        *(ushort4*)&cl[base] = l0;
        *(ushort4*)&cl[base + 4] = l1;
    }
}

// ==================== launch =================================================
extern "C" void kernel_launch(void* const* d_in, const int* in_sizes, int n_in,
                              void* d_out, int out_size, void* d_ws, size_t ws_size,
                              hipStream_t stream) {
    const float* X  = (const float*)d_in[0];
    const float* Wq = (const float*)d_in[1];
    const float* bq = (const float*)d_in[2];
    const float* Wk = (const float*)d_in[3];
    const float* bk = (const float*)d_in[4];
    const float* Wv = (const float*)d_in[5];
    const float* bv = (const float*)d_in[6];
    const float* Wo = (const float*)d_in[7];
    const float* bo = (const float*)d_in[8];
    float* out = (float*)d_out;

    // ws layout: q|k|v fp32 (100.7MB) | rope tables (1MB) |
    //            Xhi|Xlo bf16 (33.6MB, aliased by ctx hi/lo after QKV) |
    //            W{q,k,v,o} hi/lo bf16 (67.1MB)   total ~202.4MB
    const size_t QS = (size_t)NB * NH * SEQ * HD;   // 8,388,608 elems
    const size_t WS = (size_t)HIDDEN * HIDDEN;      // 4,194,304 elems
    float* q_ws = (float*)d_ws;
    float* k_ws = q_ws + QS;
    float* v_ws = k_ws + QS;
    float* cost = v_ws + QS;
    float* sint = cost + (size_t)SEQ * 64;
    ushort_t* Xh = (ushort_t*)(sint + (size_t)SEQ * 64);  // also ctx_hi
    ushort_t* Xl = Xh + QS;                               // also ctx_lo
    ushort_t* Wh[4], *Wl[4];
    ushort_t* wp = Xl + QS;
    for (int i = 0; i < 4; i++) { Wh[i] = wp; wp += WS; Wl[i] = wp; wp += WS; }

    k_rope_tables<<<(SEQ * 64) / 256, 256, 0, stream>>>(cost, sint);

    // splits: X (shared by QKV) + 4 weight matrices
    k_split<<<QS / 4 / 256, 256, 0, stream>>>((const float4*)X, (ushort4*)Xh, (ushort4*)Xl);
    k_split<<<WS / 4 / 256, 256, 0, stream>>>((const float4*)Wq, (ushort4*)Wh[0], (ushort4*)Wl[0]);
    k_split<<<WS / 4 / 256, 256, 0, stream>>>((const float4*)Wk, (ushort4*)Wh[1], (ushort4*)Wl[1]);
    k_split<<<WS / 4 / 256, 256, 0, stream>>>((const float4*)Wv, (ushort4*)Wh[2], (ushort4*)Wl[2]);
    k_split<<<WS / 4 / 256, 256, 0, stream>>>((const float4*)Wo, (ushort4*)Wh[3], (ushort4*)Wl[3]);

    dim3 g(32, 16);   // M=4096/128, N=2048/128
    k_gemm_mfma<<<g, 256, 0, stream>>>(Xh, Xl, Wh[0], Wl[0], bq, q_ws, 1);
    k_gemm_mfma<<<g, 256, 0, stream>>>(Xh, Xl, Wh[1], Wl[1], bk, k_ws, 1);
    k_gemm_mfma<<<g, 256, 0, stream>>>(Xh, Xl, Wh[2], Wl[2], bv, v_ws, 1);

    k_rope_apply<<<(NB * NH * SEQ * 64) / 256, 256, 0, stream>>>(q_ws, k_ws, cost, sint);

    // flash writes ctx split over the (now dead) X-split region
    k_flash<<<dim3(SEQ / 64, NH, NB), 256, 0, stream>>>(q_ws, k_ws, v_ws, Xh, Xl);

    k_gemm_mfma<<<g, 256, 0, stream>>>(Xh, Xl, Wh[3], Wl[3], bo, out, 0);
}

// Round 3
// 703.746 us; speedup vs baseline: 5.4107x; 2.9196x over previous
//
#include <hip/hip_runtime.h>
#include <math.h>

#define HIDDEN 2048
#define NH 16
#define HD 128
#define NB 2
#define SEQ 2048
#define K_DIM 2048

typedef unsigned int u32;
typedef unsigned short ushort_t;
typedef __bf16 bf16x8 __attribute__((ext_vector_type(8)));
typedef float f32x4 __attribute__((ext_vector_type(4)));
typedef ushort_t u16x8 __attribute__((ext_vector_type(8)));

// ---------- fp32 -> (bf16 hi, bf16 lo) split, RNE both halves ----------
__device__ __forceinline__ void split1(float x, unsigned short& h, unsigned short& l) {
    u32 u = __float_as_uint(x);
    u32 hr = (u + 0x7FFFu + ((u >> 16) & 1u)) >> 16;
    h = (unsigned short)hr;
    float r = x - __uint_as_float(hr << 16);
    u32 u2 = __float_as_uint(r);
    l = (unsigned short)((u2 + 0x7FFFu + ((u2 >> 16) & 1u)) >> 16);
}

__device__ __forceinline__ ushort_t bf16r(float x) {
    u32 u = __float_as_uint(x);
    return (ushort_t)((u + 0x7FFFu + ((u >> 16) & 1u)) >> 16);
}

__device__ __forceinline__ void gl_lds16(const void* g, void* l) {
    __builtin_amdgcn_global_load_lds(
        (const __attribute__((address_space(1))) u32*)g,
        (__attribute__((address_space(3))) u32*)l, 16, 0, 0);
}

// ==================== RoPE tables (double-precision trig) ====================
__global__ void k_rope_tables(float* __restrict__ ct, float* __restrict__ st) {
    int idx = blockIdx.x * 256 + threadIdx.x;   // exactly SEQ*64 threads
    int s = idx >> 6, d = idx & 63;
    double inv = pow(10000.0, -(double)d * (1.0 / 64.0));
    double ang = (double)s * inv;
    ct[idx] = (float)cos(ang);
    st[idx] = (float)sin(ang);
}

// ==================== fp32 -> bf16 hi/lo split kernel ========================
__global__ void k_split(const float4* __restrict__ src, ushort4* __restrict__ hi,
                        ushort4* __restrict__ lo) {
    int idx = blockIdx.x * 256 + threadIdx.x;
    float4 x = src[idx];
    ushort4 h, l;
    split1(x.x, h.x, l.x);
    split1(x.y, h.y, l.y);
    split1(x.z, h.z, l.z);
    split1(x.w, h.w, l.w);
    hi[idx] = h;
    lo[idx] = l;
}

// ==================== bf16x3 MFMA GEMM (unchanged from R2) ===================
__global__ __launch_bounds__(256)
void k_gemm_mfma(const ushort_t* __restrict__ Ah, const ushort_t* __restrict__ Al,
                 const ushort_t* __restrict__ Bh, const ushort_t* __restrict__ Bl,
                 const float* __restrict__ bias, float* __restrict__ out,
                 const int headLayout) {
    __shared__ ushort_t lds[4][128 * 32];   // Ah | Al | Bh | Bl tiles, 32 KB
    const int tid = threadIdx.x;
    const int lane = tid & 63;
    const int w = tid >> 6;
    const int wm = w & 1, wn = w >> 1;
    const int quad = lane >> 4;
    const int l15 = lane & 15;
    const int m0 = blockIdx.x << 7;
    const int n0 = blockIdx.y << 7;

    const ushort_t* src = (w == 0) ? Ah : (w == 1) ? Al : (w == 2) ? Bh : Bl;
    const int rbase = (w < 2) ? m0 : n0;
    const int lrow = lane >> 2;
    const int lk = (lane & 3) << 3;
    const ushort_t* gp[8];
    ushort_t* lp[8];
#pragma unroll
    for (int i = 0; i < 8; i++) {
        gp[i] = src + (size_t)(rbase + i * 16 + lrow) * K_DIM + lk;
        lp[i] = &lds[w][i * 512];
    }

    f32x4 acc[4][4];
#pragma unroll
    for (int i = 0; i < 4; i++)
#pragma unroll
        for (int j = 0; j < 4; j++) acc[i][j] = (f32x4){0.f, 0.f, 0.f, 0.f};

    const int aoff = (wm * 64 + l15) * 32 + quad * 8;
    const int boff = (wn * 64 + l15) * 32 + quad * 8;

#pragma unroll
    for (int i = 0; i < 8; i++) gl_lds16(gp[i], lp[i]);
    __syncthreads();
    bf16x8 ah[4], al[4], bh[4], bl[4];
#pragma unroll
    for (int f = 0; f < 4; f++) {
        ah[f] = *(const bf16x8*)&lds[0][aoff + f * 512];
        al[f] = *(const bf16x8*)&lds[1][aoff + f * 512];
        bh[f] = *(const bf16x8*)&lds[2][boff + f * 512];
        bl[f] = *(const bf16x8*)&lds[3][boff + f * 512];
    }

    for (int kt = 32; kt <= K_DIM; kt += 32) {
        __syncthreads();
        if (kt < K_DIM) {
#pragma unroll
            for (int i = 0; i < 8; i++) gl_lds16(gp[i] + kt, lp[i]);
        }
#pragma unroll
        for (int fm = 0; fm < 4; fm++)
#pragma unroll
            for (int fn = 0; fn < 4; fn++) {
                acc[fm][fn] = __builtin_amdgcn_mfma_f32_16x16x32_bf16(ah[fm], bh[fn], acc[fm][fn], 0, 0, 0);
                acc[fm][fn] = __builtin_amdgcn_mfma_f32_16x16x32_bf16(ah[fm], bl[fn], acc[fm][fn], 0, 0, 0);
                acc[fm][fn] = __builtin_amdgcn_mfma_f32_16x16x32_bf16(al[fm], bh[fn], acc[fm][fn], 0, 0, 0);
            }
        if (kt < K_DIM) {
            __syncthreads();
#pragma unroll
            for (int f = 0; f < 4; f++) {
                ah[f] = *(const bf16x8*)&lds[0][aoff + f * 512];
                al[f] = *(const bf16x8*)&lds[1][aoff + f * 512];
                bh[f] = *(const bf16x8*)&lds[2][boff + f * 512];
                bl[f] = *(const bf16x8*)&lds[3][boff + f * 512];
            }
        }
    }

    float bcolv[4];
#pragma unroll
    for (int fn = 0; fn < 4; fn++) bcolv[fn] = bias[n0 + wn * 64 + fn * 16 + l15];

    if (headLayout) {
        const int h = n0 >> 7;
        const int bb = m0 >> 11;
        const int sb = (m0 & (SEQ - 1)) + wm * 64 + quad * 4;
        const int d = wn * 64 + l15;
        float* obase = out + ((size_t)(bb * NH + h) * SEQ) * HD;
#pragma unroll
        for (int fm = 0; fm < 4; fm++)
#pragma unroll
            for (int fn = 0; fn < 4; fn++)
#pragma unroll
                for (int r = 0; r < 4; r++)
                    obase[(size_t)(sb + fm * 16 + r) * HD + d + fn * 16] =
                        acc[fm][fn][r] + bcolv[fn];
    } else {
        const int mb = m0 + wm * 64 + quad * 4;
        const int nb = n0 + wn * 64 + l15;
#pragma unroll
        for (int fm = 0; fm < 4; fm++)
#pragma unroll
            for (int fn = 0; fn < 4; fn++)
#pragma unroll
                for (int r = 0; r < 4; r++)
                    out[(size_t)(mb + fm * 16 + r) * HIDDEN + nb + fn * 16] =
                        acc[fm][fn][r] + bcolv[fn];
    }
}

// ==================== RoPE + pack to bf16 (Q scaled by 1/sqrt(HD)) ===========
__global__ void k_rope_pack(const float* __restrict__ q, const float* __restrict__ k,
                            const float* __restrict__ ct, const float* __restrict__ st,
                            ushort_t* __restrict__ Qb, ushort_t* __restrict__ Kb) {
    int idx = blockIdx.x * 256 + threadIdx.x;   // exactly NB*NH*SEQ*64 threads
    int d = idx & 63;
    int s = (idx >> 6) & (SEQ - 1);
    int bh = idx >> 17;
    size_t base = ((size_t)bh * SEQ + s) * HD;
    float c = ct[(s << 6) + d], sn = st[(s << 6) + d];
    const float scq = 0.08838834764831845f;
    float q0 = q[base + d], q1 = q[base + d + 64];
    Qb[base + d]      = bf16r((q0 * c - q1 * sn) * scq);
    Qb[base + d + 64] = bf16r((q1 * c + q0 * sn) * scq);
    float k0 = k[base + d], k1 = k[base + d + 64];
    Kb[base + d]      = bf16r(k0 * c - k1 * sn);
    Kb[base + d + 64] = bf16r(k1 * c + k0 * sn);
}

// ==================== V transpose + pack: (B,H,S,D) fp32 -> (B,H,D,S) bf16 ===
__global__ __launch_bounds__(256)
void k_vpack(const float* __restrict__ v, ushort_t* __restrict__ vt) {
    __shared__ float t[64][65];
    const int tid = threadIdx.x;
    const int bh = blockIdx.z;
    const int s0 = blockIdx.x << 6;
    const int d0 = blockIdx.y << 6;
    const float* src = v + ((size_t)bh * SEQ + s0) * HD + d0;
    const int rr = tid >> 4;            // 0..15
    const int cc = (tid & 15) << 2;     // 0..60
#pragma unroll
    for (int i = 0; i < 4; i++) {
        float4 x = *(const float4*)(src + (size_t)(i * 16 + rr) * HD + cc);
        t[i * 16 + rr][cc] = x.x;
        t[i * 16 + rr][cc + 1] = x.y;
        t[i * 16 + rr][cc + 2] = x.z;
        t[i * 16 + rr][cc + 3] = x.w;
    }
    __syncthreads();
    const int dr = tid >> 2;            // 0..63
    const int sc_ = (tid & 3) << 4;     // 0,16,32,48
    ushort_t* dst = vt + ((size_t)bh * HD + d0 + dr) * SEQ + s0 + sc_;
    u16x8 o0, o1;
#pragma unroll
    for (int u = 0; u < 8; u++) o0[u] = bf16r(t[sc_ + u][dr]);
#pragma unroll
    for (int u = 0; u < 8; u++) o1[u] = bf16r(t[sc_ + 8 + u][dr]);
    *(u16x8*)dst = o0;
    *(u16x8*)(dst + 8) = o1;
}

// ==================== MFMA flash attention ===================================
// Block = 256 thr = 4 waves; 128 q rows (32/wave), K-chunks of 128.
// Q frags in registers; K/V share one padded LDS buffer; P via LDS (bf16).
// Fragment layouts per guide: A/B row-major 8-contig @ quad*8; C/D col=l15,
// row=quad*4+r [m89/m91]. Softmax fp32, PV bf16, acc fp32.
__global__ __launch_bounds__(256, 2)
void k_flash_mfma(const ushort_t* __restrict__ Qb, const ushort_t* __restrict__ Kb,
                  const ushort_t* __restrict__ Vt,
                  ushort_t* __restrict__ ch, ushort_t* __restrict__ cl) {
    __shared__ ushort_t KV[128 * 136];
    __shared__ ushort_t Ps[128 * 136];
    const int tid = threadIdx.x;
    const int lane = tid & 63;
    const int w = tid >> 6;
    const int quad = lane >> 4;
    const int l15 = lane & 15;
    const int qt = blockIdx.x, h = blockIdx.y, b = blockIdx.z;
    const size_t bh = (size_t)(b * NH + h);
    const ushort_t* Qg = Qb + (bh * SEQ + ((size_t)qt << 7)) * HD;
    const ushort_t* Kg = Kb + bh * SEQ * HD;
    const ushort_t* Vg = Vt + bh * HD * SEQ;

    // persistent Q fragments: rows w*32+qi*16+l15, k = ks*32+quad*8 (16B global)
    bf16x8 qf[2][4];
#pragma unroll
    for (int qi = 0; qi < 2; qi++)
#pragma unroll
        for (int ks = 0; ks < 4; ks++)
            qf[qi][ks] = *(const bf16x8*)(Qg + (size_t)(w * 32 + qi * 16 + l15) * HD + ks * 32 + quad * 8);

    f32x4 acc[2][8];
#pragma unroll
    for (int qi = 0; qi < 2; qi++)
#pragma unroll
        for (int d = 0; d < 8; d++) acc[qi][d] = (f32x4){0.f, 0.f, 0.f, 0.f};
    float m_run[2][4], l_run[2][4];
#pragma unroll
    for (int qi = 0; qi < 2; qi++)
#pragma unroll
        for (int r = 0; r < 4; r++) { m_run[qi][r] = -1e30f; l_run[qi][r] = 0.f; }

    const int sr = tid >> 4;            // staging row 0..15 (per 16-row group)
    const int sc8 = (tid & 15) << 3;    // staging col offset (8 elems = 16B)

    for (int kt = 0; kt < SEQ; kt += 128) {
        __syncthreads();                // prev chunk's PV reads done
#pragma unroll
        for (int i = 0; i < 8; i++)     // stage K chunk (coalesced 16B)
            *(u16x8*)&KV[(i * 16 + sr) * 136 + sc8] =
                *(const u16x8*)(Kg + (size_t)(kt + i * 16 + sr) * HD + sc8);
        __syncthreads();

        // ---- scores: sc[qi][j] = Q(16 rows) x K(16 rows)^T, K=128 ----
        f32x4 sc[2][8];
#pragma unroll
        for (int qi = 0; qi < 2; qi++)
#pragma unroll
            for (int j = 0; j < 8; j++) sc[qi][j] = (f32x4){0.f, 0.f, 0.f, 0.f};
#pragma unroll
        for (int ks = 0; ks < 4; ks++) {
            bf16x8 kf[8];
#pragma unroll
            for (int j = 0; j < 8; j++)
                kf[j] = *(const bf16x8*)&KV[(j * 16 + l15) * 136 + ks * 32 + quad * 8];
#pragma unroll
            for (int qi = 0; qi < 2; qi++)
#pragma unroll
                for (int j = 0; j < 8; j++)
                    sc[qi][j] = __builtin_amdgcn_mfma_f32_16x16x32_bf16(qf[qi][ks], kf[j], sc[qi][j], 0, 0, 0);
        }

        // ---- online softmax (fp32); P -> LDS as bf16 in A-operand layout ----
        float alpha[2][4];
#pragma unroll
        for (int qi = 0; qi < 2; qi++)
#pragma unroll
            for (int r = 0; r < 4; r++) {
                float mx = sc[qi][0][r];
#pragma unroll
                for (int j = 1; j < 8; j++) mx = fmaxf(mx, sc[qi][j][r]);
                mx = fmaxf(mx, __shfl_xor(mx, 1));
                mx = fmaxf(mx, __shfl_xor(mx, 2));
                mx = fmaxf(mx, __shfl_xor(mx, 4));
                mx = fmaxf(mx, __shfl_xor(mx, 8));
                float mn = fmaxf(m_run[qi][r], mx);
                float al = __expf(m_run[qi][r] - mn);
                m_run[qi][r] = mn;
                alpha[qi][r] = al;
                float ls = 0.f;
                const int prow = (w * 32 + qi * 16 + quad * 4 + r) * 136 + l15;
#pragma unroll
                for (int j = 0; j < 8; j++) {
                    float p = __expf(sc[qi][j][r] - mn);
                    Ps[prow + j * 16] = bf16r(p);
                    ls += p;
                }
                ls += __shfl_xor(ls, 1);
                ls += __shfl_xor(ls, 2);
                ls += __shfl_xor(ls, 4);
                ls += __shfl_xor(ls, 8);
                l_run[qi][r] = l_run[qi][r] * al + ls;
            }
#pragma unroll
        for (int qi = 0; qi < 2; qi++)
#pragma unroll
            for (int d = 0; d < 8; d++)
#pragma unroll
                for (int r = 0; r < 4; r++) acc[qi][d][r] *= alpha[qi][r];

        __syncthreads();                // K reads + Ps writes complete
#pragma unroll
        for (int i = 0; i < 8; i++)     // stage V chunk (transposed layout)
            *(u16x8*)&KV[(i * 16 + sr) * 136 + sc8] =
                *(const u16x8*)(Vg + (size_t)(i * 16 + sr) * SEQ + kt + sc8);
        __syncthreads();

        // ---- PV: acc[qi][d] += P(16 rows x 128) x V^T tile ----
#pragma unroll
        for (int ks = 0; ks < 4; ks++) {
            bf16x8 pf[2], vf[8];
#pragma unroll
            for (int qi = 0; qi < 2; qi++)
                pf[qi] = *(const bf16x8*)&Ps[(w * 32 + qi * 16 + l15) * 136 + ks * 32 + quad * 8];
#pragma unroll
            for (int d = 0; d < 8; d++)
                vf[d] = *(const bf16x8*)&KV[(d * 16 + l15) * 136 + ks * 32 + quad * 8];
#pragma unroll
            for (int qi = 0; qi < 2; qi++)
#pragma unroll
                for (int d = 0; d < 8; d++)
                    acc[qi][d] = __builtin_amdgcn_mfma_f32_16x16x32_bf16(pf[qi], vf[d], acc[qi][d], 0, 0, 0);
        }
    }

    // ---- epilogue: normalize, split to bf16 hi/lo ctx (B,S,H) ----
#pragma unroll
    for (int qi = 0; qi < 2; qi++)
#pragma unroll
        for (int r = 0; r < 4; r++) {
            float inv = 1.0f / l_run[qi][r];
            int s = (qt << 7) + w * 32 + qi * 16 + quad * 4 + r;
            size_t base = ((size_t)b * SEQ + s) * HIDDEN + (h << 7) + l15;
#pragma unroll
            for (int d = 0; d < 8; d++) {
                ushort_t hh, ll;
                split1(acc[qi][d][r] * inv, hh, ll);
                ch[base + d * 16] = hh;
                cl[base + d * 16] = ll;
            }
        }
}

// ==================== launch =================================================
extern "C" void kernel_launch(void* const* d_in, const int* in_sizes, int n_in,
                              void* d_out, int out_size, void* d_ws, size_t ws_size,
                              hipStream_t stream) {
    const float* X  = (const float*)d_in[0];
    const float* Wq = (const float*)d_in[1];
    const float* bq = (const float*)d_in[2];
    const float* Wk = (const float*)d_in[3];
    const float* bk = (const float*)d_in[4];
    const float* Wv = (const float*)d_in[5];
    const float* bv = (const float*)d_in[6];
    const float* Wo = (const float*)d_in[7];
    const float* bo = (const float*)d_in[8];
    float* out = (float*)d_out;

    // ws: q|k|v fp32 (100.7MB) | rope tables (1MB) | Xh|Xl bf16 (33.6MB,
    // reused as Qb|Kb) | W hi/lo x4 (67.1MB) | Vtb bf16 (16.8MB)  ~219MB.
    // ctx hi/lo aliases dead q_ws after flash inputs are packed.
    const size_t QS = (size_t)NB * NH * SEQ * HD;   // 8,388,608 elems
    const size_t WS = (size_t)HIDDEN * HIDDEN;      // 4,194,304 elems
    float* q_ws = (float*)d_ws;
    float* k_ws = q_ws + QS;
    float* v_ws = k_ws + QS;
    float* cost = v_ws + QS;
    float* sint = cost + (size_t)SEQ * 64;
    ushort_t* Xh = (ushort_t*)(sint + (size_t)SEQ * 64);  // -> Qb after QKV
    ushort_t* Xl = Xh + QS;                               // -> Kb after QKV
    ushort_t* Wh[4], *Wl[4];
    ushort_t* wp = Xl + QS;
    for (int i = 0; i < 4; i++) { Wh[i] = wp; wp += WS; Wl[i] = wp; wp += WS; }
    ushort_t* Vtb = wp;                                   // bf16 V^T
    ushort_t* ctxh = (ushort_t*)q_ws;                     // ctx hi/lo over dead q_ws
    ushort_t* ctxl = ctxh + QS;

    k_rope_tables<<<(SEQ * 64) / 256, 256, 0, stream>>>(cost, sint);

    k_split<<<QS / 4 / 256, 256, 0, stream>>>((const float4*)X, (ushort4*)Xh, (ushort4*)Xl);
    k_split<<<WS / 4 / 256, 256, 0, stream>>>((const float4*)Wq, (ushort4*)Wh[0], (ushort4*)Wl[0]);
    k_split<<<WS / 4 / 256, 256, 0, stream>>>((const float4*)Wk, (ushort4*)Wh[1], (ushort4*)Wl[1]);
    k_split<<<WS / 4 / 256, 256, 0, stream>>>((const float4*)Wv, (ushort4*)Wh[2], (ushort4*)Wl[2]);
    k_split<<<WS / 4 / 256, 256, 0, stream>>>((const float4*)Wo, (ushort4*)Wh[3], (ushort4*)Wl[3]);

    dim3 g(32, 16);
    k_gemm_mfma<<<g, 256, 0, stream>>>(Xh, Xl, Wh[0], Wl[0], bq, q_ws, 1);
    k_gemm_mfma<<<g, 256, 0, stream>>>(Xh, Xl, Wh[1], Wl[1], bk, k_ws, 1);
    k_gemm_mfma<<<g, 256, 0, stream>>>(Xh, Xl, Wh[2], Wl[2], bv, v_ws, 1);

    // pack: rope->bf16 Q,K over the dead X-split region; V -> transposed bf16
    ushort_t* Qbb = Xh;
    ushort_t* Kbb = Xl;
    k_rope_pack<<<(NB * NH * SEQ * 64) / 256, 256, 0, stream>>>(q_ws, k_ws, cost, sint, Qbb, Kbb);
    k_vpack<<<dim3(SEQ / 64, HD / 64, NB * NH), 256, 0, stream>>>(v_ws, Vtb);

    k_flash_mfma<<<dim3(SEQ / 128, NH, NB), 256, 0, stream>>>(Qbb, Kbb, Vtb, ctxh, ctxl);

    k_gemm_mfma<<<g, 256, 0, stream>>>(ctxh, ctxl, Wh[3], Wl[3], bo, out, 0);
}

// Round 4
// 540.497 us; speedup vs baseline: 7.0449x; 1.3020x over previous
//
#include <hip/hip_runtime.h>
#include <hip/hip_bf16.h>
#include <math.h>

#define HIDDEN 2048
#define NH 16
#define HD 128
#define NB 2
#define SEQ 2048
#define K_DIM 2048

typedef unsigned int u32;
typedef unsigned short ushort_t;
typedef __bf16 bf16x8 __attribute__((ext_vector_type(8)));
typedef float f32x4 __attribute__((ext_vector_type(4)));
typedef ushort_t u16x8 __attribute__((ext_vector_type(8)));

// ---------- fp32 -> (bf16 hi, bf16 lo) split, RNE both halves ----------
__device__ __forceinline__ void split1(float x, unsigned short& h, unsigned short& l) {
    u32 u = __float_as_uint(x);
    u32 hr = (u + 0x7FFFu + ((u >> 16) & 1u)) >> 16;
    h = (unsigned short)hr;
    float r = x - __uint_as_float(hr << 16);
    u32 u2 = __float_as_uint(r);
    l = (unsigned short)((u2 + 0x7FFFu + ((u2 >> 16) & 1u)) >> 16);
}

__device__ __forceinline__ ushort_t bf16r(float x) {
    u32 u = __float_as_uint(x);
    return (ushort_t)((u + 0x7FFFu + ((u >> 16) & 1u)) >> 16);
}

__device__ __forceinline__ void gl_lds16(const void* g, void* l) {
    __builtin_amdgcn_global_load_lds(
        (const __attribute__((address_space(1))) u32*)g,
        (__attribute__((address_space(3))) u32*)l, 16, 0, 0);
}

// ==================== RoPE tables (double-precision trig) ====================
__global__ void k_rope_tables(float* __restrict__ ct, float* __restrict__ st) {
    int idx = blockIdx.x * 256 + threadIdx.x;   // exactly SEQ*64 threads
    int s = idx >> 6, d = idx & 63;
    double inv = pow(10000.0, -(double)d * (1.0 / 64.0));
    double ang = (double)s * inv;
    ct[idx] = (float)cos(ang);
    st[idx] = (float)sin(ang);
}

// ==================== fused fp32 -> bf16 (hi only) for X, Wq, Wk, Wv ========
#define XG 2097152   // X float4 groups
#define WG 1048576   // W float4 groups
__global__ void k_cvt_all(const float4* __restrict__ X, const float4* __restrict__ W0,
                          const float4* __restrict__ W1, const float4* __restrict__ W2,
                          ushort4* __restrict__ Xh, ushort4* __restrict__ H0,
                          ushort4* __restrict__ H1, ushort4* __restrict__ H2) {
    int idx = blockIdx.x * 256 + threadIdx.x;   // XG + 3*WG threads
    const float4* src;
    ushort4* dst;
    int off;
    if (idx < XG) { src = X; dst = Xh; off = idx; }
    else {
        int t = idx - XG;
        int m = t >> 20;        // WG = 2^20
        off = t & (WG - 1);
        src = (m == 0) ? W0 : (m == 1) ? W1 : W2;
        dst = (m == 0) ? H0 : (m == 1) ? H1 : H2;
    }
    float4 x = src[off];
    ushort4 h;
    h.x = bf16r(x.x); h.y = bf16r(x.y); h.z = bf16r(x.z); h.w = bf16r(x.w);
    dst[off] = h;
}

// ==================== fp32 -> bf16 hi/lo split (Wo only) =====================
__global__ void k_split(const float4* __restrict__ src, ushort4* __restrict__ hi,
                        ushort4* __restrict__ lo) {
    int idx = blockIdx.x * 256 + threadIdx.x;
    float4 x = src[idx];
    ushort4 h, l;
    split1(x.x, h.x, l.x);
    split1(x.y, h.y, l.y);
    split1(x.z, h.z, l.z);
    split1(x.w, h.w, l.w);
    hi[idx] = h;
    lo[idx] = l;
}

// ==================== fused QKV plain-bf16 MFMA GEMM =========================
// grid (32, 48): blockIdx.y>>4 selects {q,k,v}; 128x128 tile, BK=32, m97-style.
// out scatter: (B,NH,S,HD) fp32.
__global__ __launch_bounds__(256)
void k_gemm_qkv(const ushort_t* __restrict__ Xh,
                const ushort_t* __restrict__ W0, const ushort_t* __restrict__ W1,
                const ushort_t* __restrict__ W2,
                const float* __restrict__ b0, const float* __restrict__ b1,
                const float* __restrict__ b2,
                float* __restrict__ o0, float* __restrict__ o1, float* __restrict__ o2) {
    __shared__ ushort_t As[128 * 32];
    __shared__ ushort_t Bs[128 * 32];
    const int tid = threadIdx.x;
    const int lane = tid & 63;
    const int w = tid >> 6;
    const int wm = w & 1, wn = w >> 1;
    const int quad = lane >> 4;
    const int l15 = lane & 15;
    const int m0 = blockIdx.x << 7;
    const int mat = blockIdx.y >> 4;
    const int n0 = (blockIdx.y & 15) << 7;
    const ushort_t* Wsel = (mat == 0) ? W0 : (mat == 1) ? W1 : W2;
    const float* bias = (mat == 0) ? b0 : (mat == 1) ? b1 : b2;
    float* out = (mat == 0) ? o0 : (mat == 1) ? o1 : o2;

    // staging: waves 0,1 -> As halves; waves 2,3 -> Bs halves. 4 instrs/wave.
    const ushort_t* src = (w < 2) ? Xh : Wsel;
    const int rbase = ((w < 2) ? m0 : n0) + (w & 1) * 64;
    ushort_t* lbase = ((w < 2) ? As : Bs) + (w & 1) * 64 * 32;
    const int lrow = lane >> 2;
    const int lk = (lane & 3) << 3;
    const ushort_t* gp[4];
    ushort_t* lp[4];
#pragma unroll
    for (int i = 0; i < 4; i++) {
        gp[i] = src + (size_t)(rbase + i * 16 + lrow) * K_DIM + lk;
        lp[i] = lbase + i * 512;
    }

    f32x4 acc[4][4];
#pragma unroll
    for (int i = 0; i < 4; i++)
#pragma unroll
        for (int j = 0; j < 4; j++) acc[i][j] = (f32x4){0.f, 0.f, 0.f, 0.f};

    const int aoff = (wm * 64 + l15) * 32 + quad * 8;
    const int boff = (wn * 64 + l15) * 32 + quad * 8;

#pragma unroll
    for (int i = 0; i < 4; i++) gl_lds16(gp[i], lp[i]);
    __syncthreads();
    bf16x8 ah[4], bh[4];
#pragma unroll
    for (int f = 0; f < 4; f++) {
        ah[f] = *(const bf16x8*)&As[aoff + f * 512];
        bh[f] = *(const bf16x8*)&Bs[boff + f * 512];
    }

    for (int kt = 32; kt <= K_DIM; kt += 32) {
        __syncthreads();
        if (kt < K_DIM) {
#pragma unroll
            for (int i = 0; i < 4; i++) gl_lds16(gp[i] + kt, lp[i]);
        }
#pragma unroll
        for (int fm = 0; fm < 4; fm++)
#pragma unroll
            for (int fn = 0; fn < 4; fn++)
                acc[fm][fn] = __builtin_amdgcn_mfma_f32_16x16x32_bf16(ah[fm], bh[fn], acc[fm][fn], 0, 0, 0);
        if (kt < K_DIM) {
            __syncthreads();
#pragma unroll
            for (int f = 0; f < 4; f++) {
                ah[f] = *(const bf16x8*)&As[aoff + f * 512];
                bh[f] = *(const bf16x8*)&Bs[boff + f * 512];
            }
        }
    }

    float bcolv[4];
#pragma unroll
    for (int fn = 0; fn < 4; fn++) bcolv[fn] = bias[n0 + wn * 64 + fn * 16 + l15];

    const int h = n0 >> 7;
    const int bb = m0 >> 11;
    const int sb = (m0 & (SEQ - 1)) + wm * 64 + quad * 4;
    const int d = wn * 64 + l15;
    float* obase = out + ((size_t)(bb * NH + h) * SEQ) * HD;
#pragma unroll
    for (int fm = 0; fm < 4; fm++)
#pragma unroll
        for (int fn = 0; fn < 4; fn++)
#pragma unroll
            for (int r = 0; r < 4; r++)
                obase[(size_t)(sb + fm * 16 + r) * HD + d + fn * 16] =
                    acc[fm][fn][r] + bcolv[fn];
}

// ==================== bf16x3 MFMA GEMM (O-projection, unchanged) =============
__global__ __launch_bounds__(256)
void k_gemm_mfma(const ushort_t* __restrict__ Ah, const ushort_t* __restrict__ Al,
                 const ushort_t* __restrict__ Bh, const ushort_t* __restrict__ Bl,
                 const float* __restrict__ bias, float* __restrict__ out) {
    __shared__ ushort_t lds[4][128 * 32];
    const int tid = threadIdx.x;
    const int lane = tid & 63;
    const int w = tid >> 6;
    const int wm = w & 1, wn = w >> 1;
    const int quad = lane >> 4;
    const int l15 = lane & 15;
    const int m0 = blockIdx.x << 7;
    const int n0 = blockIdx.y << 7;

    const ushort_t* src = (w == 0) ? Ah : (w == 1) ? Al : (w == 2) ? Bh : Bl;
    const int rbase = (w < 2) ? m0 : n0;
    const int lrow = lane >> 2;
    const int lk = (lane & 3) << 3;
    const ushort_t* gp[8];
    ushort_t* lp[8];
#pragma unroll
    for (int i = 0; i < 8; i++) {
        gp[i] = src + (size_t)(rbase + i * 16 + lrow) * K_DIM + lk;
        lp[i] = &lds[w][i * 512];
    }

    f32x4 acc[4][4];
#pragma unroll
    for (int i = 0; i < 4; i++)
#pragma unroll
        for (int j = 0; j < 4; j++) acc[i][j] = (f32x4){0.f, 0.f, 0.f, 0.f};

    const int aoff = (wm * 64 + l15) * 32 + quad * 8;
    const int boff = (wn * 64 + l15) * 32 + quad * 8;

#pragma unroll
    for (int i = 0; i < 8; i++) gl_lds16(gp[i], lp[i]);
    __syncthreads();
    bf16x8 ah[4], al[4], bh[4], bl[4];
#pragma unroll
    for (int f = 0; f < 4; f++) {
        ah[f] = *(const bf16x8*)&lds[0][aoff + f * 512];
        al[f] = *(const bf16x8*)&lds[1][aoff + f * 512];
        bh[f] = *(const bf16x8*)&lds[2][boff + f * 512];
        bl[f] = *(const bf16x8*)&lds[3][boff + f * 512];
    }

    for (int kt = 32; kt <= K_DIM; kt += 32) {
        __syncthreads();
        if (kt < K_DIM) {
#pragma unroll
            for (int i = 0; i < 8; i++) gl_lds16(gp[i] + kt, lp[i]);
        }
#pragma unroll
        for (int fm = 0; fm < 4; fm++)
#pragma unroll
            for (int fn = 0; fn < 4; fn++) {
                acc[fm][fn] = __builtin_amdgcn_mfma_f32_16x16x32_bf16(ah[fm], bh[fn], acc[fm][fn], 0, 0, 0);
                acc[fm][fn] = __builtin_amdgcn_mfma_f32_16x16x32_bf16(ah[fm], bl[fn], acc[fm][fn], 0, 0, 0);
                acc[fm][fn] = __builtin_amdgcn_mfma_f32_16x16x32_bf16(al[fm], bh[fn], acc[fm][fn], 0, 0, 0);
            }
        if (kt < K_DIM) {
            __syncthreads();
#pragma unroll
            for (int f = 0; f < 4; f++) {
                ah[f] = *(const bf16x8*)&lds[0][aoff + f * 512];
                al[f] = *(const bf16x8*)&lds[1][aoff + f * 512];
                bh[f] = *(const bf16x8*)&lds[2][boff + f * 512];
                bl[f] = *(const bf16x8*)&lds[3][boff + f * 512];
            }
        }
    }

    float bcolv[4];
#pragma unroll
    for (int fn = 0; fn < 4; fn++) bcolv[fn] = bias[n0 + wn * 64 + fn * 16 + l15];

    const int mb = m0 + wm * 64 + quad * 4;
    const int nb = n0 + wn * 64 + l15;
#pragma unroll
    for (int fm = 0; fm < 4; fm++)
#pragma unroll
        for (int fn = 0; fn < 4; fn++)
#pragma unroll
            for (int r = 0; r < 4; r++)
                out[(size_t)(mb + fm * 16 + r) * HIDDEN + nb + fn * 16] =
                    acc[fm][fn][r] + bcolv[fn];
}

// ==================== RoPE + pack to bf16 (Q scaled by 1/sqrt(HD)) ===========
__global__ void k_rope_pack(const float* __restrict__ q, const float* __restrict__ k,
                            const float* __restrict__ ct, const float* __restrict__ st,
                            ushort_t* __restrict__ Qb, ushort_t* __restrict__ Kb) {
    int idx = blockIdx.x * 256 + threadIdx.x;   // exactly NB*NH*SEQ*64 threads
    int d = idx & 63;
    int s = (idx >> 6) & (SEQ - 1);
    int bh = idx >> 17;
    size_t base = ((size_t)bh * SEQ + s) * HD;
    float c = ct[(s << 6) + d], sn = st[(s << 6) + d];
    const float scq = 0.08838834764831845f;
    float q0 = q[base + d], q1 = q[base + d + 64];
    Qb[base + d]      = bf16r((q0 * c - q1 * sn) * scq);
    Qb[base + d + 64] = bf16r((q1 * c + q0 * sn) * scq);
    float k0 = k[base + d], k1 = k[base + d + 64];
    Kb[base + d]      = bf16r(k0 * c - k1 * sn);
    Kb[base + d + 64] = bf16r(k1 * c + k0 * sn);
}

// ==================== V transpose + pack: (B,H,S,D) fp32 -> (B,H,D,S) bf16 ===
__global__ __launch_bounds__(256)
void k_vpack(const float* __restrict__ v, ushort_t* __restrict__ vt) {
    __shared__ float t[64][65];
    const int tid = threadIdx.x;
    const int bh = blockIdx.z;
    const int s0 = blockIdx.x << 6;
    const int d0 = blockIdx.y << 6;
    const float* src = v + ((size_t)bh * SEQ + s0) * HD + d0;
    const int rr = tid >> 4;
    const int cc = (tid & 15) << 2;
#pragma unroll
    for (int i = 0; i < 4; i++) {
        float4 x = *(const float4*)(src + (size_t)(i * 16 + rr) * HD + cc);
        t[i * 16 + rr][cc] = x.x;
        t[i * 16 + rr][cc + 1] = x.y;
        t[i * 16 + rr][cc + 2] = x.z;
        t[i * 16 + rr][cc + 3] = x.w;
    }
    __syncthreads();
    const int dr = tid >> 2;
    const int sc_ = (tid & 3) << 4;
    ushort_t* dst = vt + ((size_t)bh * HD + d0 + dr) * SEQ + s0 + sc_;
    u16x8 o0, o1;
#pragma unroll
    for (int u = 0; u < 8; u++) o0[u] = bf16r(t[sc_ + u][dr]);
#pragma unroll
    for (int u = 0; u < 8; u++) o1[u] = bf16r(t[sc_ + 8 + u][dr]);
    *(u16x8*)dst = o0;
    *(u16x8*)(dst + 8) = o1;
}

// ==================== MFMA flash attention, transposed scores ================
// 4 waves, 128 q-rows/block (32/wave), K-chunks of 128. Scores computed as
// K·Q^T (D rows = k-index, cols = q) so P-writes are 8B-contiguous and no
// online max is needed (|score| <= ~43, exp safe in fp32; fixed m=0).
// K/V register-prefetched one chunk ahead (global latency hidden behind the
// full chunk). PV computed as V^T·P^T -> acc rows = d, cols = q.
__global__ __launch_bounds__(256, 2)
void k_flash_mfma(const ushort_t* __restrict__ Qb, const ushort_t* __restrict__ Kb,
                  const ushort_t* __restrict__ Vt,
                  ushort_t* __restrict__ ch, ushort_t* __restrict__ cl) {
    __shared__ ushort_t KV[128 * 136];
    __shared__ ushort_t Ps[128 * 136];
    const int tid = threadIdx.x;
    const int lane = tid & 63;
    const int w = tid >> 6;
    const int quad = lane >> 4;
    const int l15 = lane & 15;
    const int qt = blockIdx.x, h = blockIdx.y, b = blockIdx.z;
    const size_t bh = (size_t)(b * NH + h);
    const ushort_t* Qg = Qb + (bh * SEQ + ((size_t)qt << 7)) * HD;
    const ushort_t* Kg = Kb + bh * SEQ * HD;
    const ushort_t* Vg = Vt + bh * HD * SEQ;

    // persistent Q fragments (B-operand): rows w*32+qi*16+l15, k = ks*32+quad*8
    bf16x8 qf[2][4];
#pragma unroll
    for (int qi = 0; qi < 2; qi++)
#pragma unroll
        for (int ks = 0; ks < 4; ks++)
            qf[qi][ks] = *(const bf16x8*)(Qg + (size_t)(w * 32 + qi * 16 + l15) * HD + ks * 32 + quad * 8);

    const int sr = tid >> 4;            // staging row 0..15
    const int sc8 = (tid & 15) << 3;    // staging col (8 elems = 16B)

    // prefetch chunk 0 K and V^T into registers
    u16x8 Kreg[8], Vreg[8];
#pragma unroll
    for (int i = 0; i < 8; i++)
        Kreg[i] = *(const u16x8*)(Kg + (size_t)(i * 16 + sr) * HD + sc8);
#pragma unroll
    for (int i = 0; i < 8; i++)
        Vreg[i] = *(const u16x8*)(Vg + (size_t)(i * 16 + sr) * SEQ + sc8);

    f32x4 acc[2][8];
#pragma unroll
    for (int qi = 0; qi < 2; qi++)
#pragma unroll
        for (int d = 0; d < 8; d++) acc[qi][d] = (f32x4){0.f, 0.f, 0.f, 0.f};
    float lp[2] = {0.f, 0.f};

    for (int kt = 0; kt < SEQ; kt += 128) {
        const int np = kt + 128;
        __syncthreads();                // prev PV reads of KV done
        // stage K_i from regs; prefetch K_{i+1}
#pragma unroll
        for (int i = 0; i < 8; i++)
            *(u16x8*)&KV[(i * 16 + sr) * 136 + sc8] = Kreg[i];
        if (np < SEQ) {
#pragma unroll
            for (int i = 0; i < 8; i++)
                Kreg[i] = *(const u16x8*)(Kg + (size_t)(np + i * 16 + sr) * HD + sc8);
        }
        __syncthreads();

        // ---- scores transposed: sc[qi][j] = K(16 rows) x Q(16 rows)^T ----
        f32x4 sc[2][8];
#pragma unroll
        for (int qi = 0; qi < 2; qi++)
#pragma unroll
            for (int j = 0; j < 8; j++) sc[qi][j] = (f32x4){0.f, 0.f, 0.f, 0.f};
#pragma unroll
        for (int ks = 0; ks < 4; ks++) {
#pragma unroll
            for (int jh = 0; jh < 2; jh++) {
                bf16x8 kf[4];
#pragma unroll
                for (int j = 0; j < 4; j++)
                    kf[j] = *(const bf16x8*)&KV[((jh * 4 + j) * 16 + l15) * 136 + ks * 32 + quad * 8];
#pragma unroll
                for (int qi = 0; qi < 2; qi++)
#pragma unroll
                    for (int j = 0; j < 4; j++)
                        sc[qi][jh * 4 + j] = __builtin_amdgcn_mfma_f32_16x16x32_bf16(
                            kf[j], qf[qi][ks], sc[qi][jh * 4 + j], 0, 0, 0);
            }
        }

        // ---- p = exp(score); accumulate l; write P (8B contiguous) ----
#pragma unroll
        for (int qi = 0; qi < 2; qi++) {
            const int prow = (w * 32 + qi * 16 + l15) * 136 + quad * 4;
#pragma unroll
            for (int j = 0; j < 8; j++) {
                float p0 = __expf(sc[qi][j][0]);
                float p1 = __expf(sc[qi][j][1]);
                float p2 = __expf(sc[qi][j][2]);
                float p3 = __expf(sc[qi][j][3]);
                lp[qi] += (p0 + p1) + (p2 + p3);
                __hip_bfloat162 lo2 = __float22bfloat162_rn({p0, p1});
                __hip_bfloat162 hi2 = __float22bfloat162_rn({p2, p3});
                uint2 pk = make_uint2(*(u32*)&lo2, *(u32*)&hi2);
                *(uint2*)&Ps[prow + j * 16] = pk;
            }
        }
        __syncthreads();                // kf reads done + Ps visible
        // stage V_i from regs; prefetch V_{i+1}
#pragma unroll
        for (int i = 0; i < 8; i++)
            *(u16x8*)&KV[(i * 16 + sr) * 136 + sc8] = Vreg[i];
        if (np < SEQ) {
#pragma unroll
            for (int i = 0; i < 8; i++)
                Vreg[i] = *(const u16x8*)(Vg + (size_t)(i * 16 + sr) * SEQ + np + sc8);
        }
        __syncthreads();

        // ---- PV transposed: acc[qi][db] = V^T(16 d-rows) x P^T ----
#pragma unroll
        for (int ks = 0; ks < 4; ks++) {
            bf16x8 pf[2];
#pragma unroll
            for (int qi = 0; qi < 2; qi++)
                pf[qi] = *(const bf16x8*)&Ps[(w * 32 + qi * 16 + l15) * 136 + ks * 32 + quad * 8];
#pragma unroll
            for (int db = 0; db < 8; db++) {
                bf16x8 vf = *(const bf16x8*)&KV[(db * 16 + l15) * 136 + ks * 32 + quad * 8];
#pragma unroll
                for (int qi = 0; qi < 2; qi++)
                    acc[qi][db] = __builtin_amdgcn_mfma_f32_16x16x32_bf16(vf, pf[qi], acc[qi][db], 0, 0, 0);
            }
        }
    }

    // ---- epilogue: reduce l across quads, normalize, split hi/lo, store ----
#pragma unroll
    for (int qi = 0; qi < 2; qi++) {
        lp[qi] += __shfl_xor(lp[qi], 16);
        lp[qi] += __shfl_xor(lp[qi], 32);
        float inv = 1.0f / lp[qi];
        int s = (qt << 7) + w * 32 + qi * 16 + l15;
        size_t base = ((size_t)b * SEQ + s) * HIDDEN + (h << 7) + quad * 4;
#pragma unroll
        for (int db = 0; db < 8; db++) {
            ushort4 hh, ll;
            split1(acc[qi][db][0] * inv, hh.x, ll.x);
            split1(acc[qi][db][1] * inv, hh.y, ll.y);
            split1(acc[qi][db][2] * inv, hh.z, ll.z);
            split1(acc[qi][db][3] * inv, hh.w, ll.w);
            *(ushort4*)&ch[base + db * 16] = hh;
            *(ushort4*)&cl[base + db * 16] = ll;
        }
    }
}

// ==================== launch =================================================
extern "C" void kernel_launch(void* const* d_in, const int* in_sizes, int n_in,
                              void* d_out, int out_size, void* d_ws, size_t ws_size,
                              hipStream_t stream) {
    const float* X  = (const float*)d_in[0];
    const float* Wq = (const float*)d_in[1];
    const float* bq = (const float*)d_in[2];
    const float* Wk = (const float*)d_in[3];
    const float* bk = (const float*)d_in[4];
    const float* Wv = (const float*)d_in[5];
    const float* bv = (const float*)d_in[6];
    const float* Wo = (const float*)d_in[7];
    const float* bo = (const float*)d_in[8];
    float* out = (float*)d_out;

    // ws: q|k|v fp32 (100.7MB) | rope tables (1MB) | Xh bf16 16.8MB (-> Qb) |
    //     Wh q,k,v bf16 (25.2MB) | Wo hi/lo (33.6MB) | Kb 16.8 | Vtb 16.8MB.
    // ctx hi/lo aliases dead q_ws after packs.
    const size_t QS = (size_t)NB * NH * SEQ * HD;   // 8,388,608 elems
    const size_t WS = (size_t)HIDDEN * HIDDEN;      // 4,194,304 elems
    float* q_ws = (float*)d_ws;
    float* k_ws = q_ws + QS;
    float* v_ws = k_ws + QS;
    float* cost = v_ws + QS;
    float* sint = cost + (size_t)SEQ * 64;
    ushort_t* Xh = (ushort_t*)(sint + (size_t)SEQ * 64);  // -> Qb after QKV
    ushort_t* Wh0 = Xh + QS;
    ushort_t* Wh1 = Wh0 + WS;
    ushort_t* Wh2 = Wh1 + WS;
    ushort_t* Woh = Wh2 + WS;
    ushort_t* Wol = Woh + WS;
    ushort_t* Kb  = Wol + WS;
    ushort_t* Vtb = Kb + QS;
    ushort_t* ctxh = (ushort_t*)q_ws;                     // over dead q_ws
    ushort_t* ctxl = ctxh + QS;

    k_rope_tables<<<(SEQ * 64) / 256, 256, 0, stream>>>(cost, sint);

    k_cvt_all<<<(XG + 3 * WG) / 256, 256, 0, stream>>>(
        (const float4*)X, (const float4*)Wq, (const float4*)Wk, (const float4*)Wv,
        (ushort4*)Xh, (ushort4*)Wh0, (ushort4*)Wh1, (ushort4*)Wh2);
    k_split<<<WS / 4 / 256, 256, 0, stream>>>((const float4*)Wo, (ushort4*)Woh, (ushort4*)Wol);

    k_gemm_qkv<<<dim3(32, 48), 256, 0, stream>>>(Xh, Wh0, Wh1, Wh2, bq, bk, bv,
                                                 q_ws, k_ws, v_ws);

    ushort_t* Qbb = Xh;   // X bf16 dead after QKV GEMM
    k_rope_pack<<<(NB * NH * SEQ * 64) / 256, 256, 0, stream>>>(q_ws, k_ws, cost, sint, Qbb, Kb);
    k_vpack<<<dim3(SEQ / 64, HD / 64, NB * NH), 256, 0, stream>>>(v_ws, Vtb);

    k_flash_mfma<<<dim3(SEQ / 128, NH, NB), 256, 0, stream>>>(Qbb, Kb, Vtb, ctxh, ctxl);

    k_gemm_mfma<<<dim3(32, 16), 256, 0, stream>>>(ctxh, ctxl, Woh, Wol, bo, out);
}